// Round 5
// baseline (1223.061 us; speedup 1.0000x reference)
//
#include <hip/hip_runtime.h>

#define BATCH 32
#define T_LEN 4096
#define NU 64
#define NX 128
#define NY 64
#define KCH 64
#define NC (T_LEN / KCH)   /* 64 chunks */

/* workspace float offsets (E/F reused as A2/A4 after solve; XT overlaps L,
   which is dead after phase2) */
#define OFF_E   0            /* 16384; becomes A2 */
#define OFF_F   16384        /* 16384; becomes A4 */
#define OFF_A   32768        /* 16384 */
#define OFF_G   49152        /* 128x256 = 32768: [A3B|A2B|AB|B] */
#define OFF_P0  81920
#define OFF_P1  98304
#define OFF_XC  114688       /* 262144 */
#define OFF_L   376832       /* 262144 (XT overlaps; L dead after phase2) */
#define OFF_XT  376832
#define XT_FLOATS ((size_t)NC * BATCH * KCH * NX)   /* 16,777,216 floats */

/* padded LDS index helpers: break stride-8/stride-16 segment bank conflicts */
__device__ __forceinline__ int XP(int l)   { return l + ((l >> 3) << 2); }  /* +4 per 8 */
__device__ __forceinline__ int UP16(int l) { return l + ((l >> 4) << 2); }  /* +4 per 16 */

/* ---- K1: E = 0.5*(S22+S11)+1e-9 I, F = S21, from M (256x256) ---- */
__global__ void ef_kernel(const float* __restrict__ M, float* __restrict__ E,
                          float* __restrict__ F) {
    int i = blockIdx.x;      // row 0..127
    int j = threadIdx.x;     // col 0..127
    const float* Mi2 = M + (size_t)(128 + i) * 256;
    const float* Mj1 = M + (size_t)j * 256;
    if (blockIdx.y == 0) {
        const float* Mi1 = M + (size_t)i * 256;
        const float* Mj2 = M + (size_t)(128 + j) * 256;
        float s11 = 0.f, s22 = 0.f;
        for (int m = 0; m < 256; ++m) {
            s11 += Mi1[m] * Mj1[m];
            s22 += Mi2[m] * Mj2[m];
        }
        float e = 0.5f * (s11 + s22);
        if (i == j) e += 1e-9f;
        E[i * NX + j] = e;
    } else {
        float s21 = 0.f;
        for (int m = 0; m < 256; ++m) s21 += Mi2[m] * Mj1[m];
        F[i * NX + j] = s21;
    }
}

/* ---- K2: solve E * A = F via register-resident Gauss-Jordan ---- */
__global__ __launch_bounds__(256) void solve_kernel(const float* __restrict__ E,
                                                    const float* __restrict__ F,
                                                    float* __restrict__ A) {
    __shared__ __align__(16) float prow[2][256];
    __shared__ float mraw[2][128];
    __shared__ float pivarr[128];
    int t = threadIdx.x;
    int w = t >> 6, lane = t & 63;
    int h = w & 1, rb = w >> 1;
    int i = rb * 64 + lane;
    const float4* src = (const float4*)((h == 0 ? E : F) + (size_t)i * NX);
    float4 R[32];
#pragma unroll
    for (int j4 = 0; j4 < 32; ++j4) R[j4] = src[j4];
    if (i == 0) {
        float4* p4 = (float4*)&prow[0][h * 128];
#pragma unroll
        for (int j4 = 0; j4 < 32; ++j4) p4[j4] = R[j4];
    }
    if (h == 0) mraw[0][i] = R[0].x;
    __syncthreads();

    for (int k = 0; k < NX; ++k) {
        int cur = k & 1, nxt = cur ^ 1;
        float piv = prow[cur][k];
        if (h == 0 && i == k) pivarr[k] = piv;
        float invp = 1.0f / piv;
        float m = mraw[cur][i] * invp;
        m = (i == k) ? 0.0f : m;
        const float4* p4 = (const float4*)&prow[cur][h * 128];
#pragma unroll
        for (int j4 = 0; j4 < 32; ++j4) {
            float4 p = p4[j4];
            R[j4].x -= m * p.x;
            R[j4].y -= m * p.y;
            R[j4].z -= m * p.z;
            R[j4].w -= m * p.w;
        }
        if (k < NX - 1) {
            if (i == k + 1) {
                float4* q4 = (float4*)&prow[nxt][h * 128];
#pragma unroll
                for (int j4 = 0; j4 < 32; ++j4) q4[j4] = R[j4];
            }
            if (h == 0) {
                int kq = (k + 1) >> 2, kr = (k + 1) & 3;
                float4 vv = R[0];
#pragma unroll
                for (int j4 = 1; j4 < 32; ++j4) if (j4 == kq) vv = R[j4];
                float val = (kr == 0) ? vv.x : (kr == 1) ? vv.y
                          : (kr == 2) ? vv.z : vv.w;
                mraw[nxt][i] = val;
            }
        }
        __syncthreads();
    }

    if (h == 1) {
        float s = 1.0f / pivarr[i];
        float4* dst = (float4*)(A + (size_t)i * NX);
#pragma unroll
        for (int j4 = 0; j4 < 32; ++j4) {
            float4 v = R[j4];
            v.x *= s; v.y *= s; v.z *= s; v.w *= s;
            dst[j4] = v;
        }
    }
}

/* ---- K3: Z = X*Y, 128x128 fp32 (squarings) ---- */
__global__ void matmul128_kernel(const float* __restrict__ X,
                                 const float* __restrict__ Y,
                                 float* __restrict__ Z) {
    int i = blockIdx.x, j = threadIdx.x;
    float a0 = 0.f, a1 = 0.f, a2 = 0.f, a3 = 0.f;
    for (int m = 0; m < NX; m += 4) {
        a0 += X[i * NX + m]     * Y[(m)     * NX + j];
        a1 += X[i * NX + m + 1] * Y[(m + 1) * NX + j];
        a2 += X[i * NX + m + 2] * Y[(m + 2) * NX + j];
        a3 += X[i * NX + m + 3] * Y[(m + 3) * NX + j];
    }
    Z[i * NX + j] = (a0 + a1) + (a2 + a3);
}

/* ---- K3b: batched small matmuls Z(128xN) = X(128x128)*Y(128xN); Y=null => copy ---- */
struct MMDesc { const float* X; const float* Y; float* Z; int N; int ldX; int ldY; int ldZ; };
struct MM3 { MMDesc d[3]; };
__global__ __launch_bounds__(128) void mm_batch_kernel(MM3 mm) {
    MMDesc d = mm.d[blockIdx.y];
    int i = blockIdx.x, j = threadIdx.x;
    if (j >= d.N) return;
    if (d.Y == nullptr) {
        d.Z[(size_t)i * d.ldZ + j] = d.X[(size_t)i * d.ldX + j];
        return;
    }
    const float* xr = d.X + (size_t)i * d.ldX;
    float a0 = 0.f, a1 = 0.f, a2 = 0.f, a3 = 0.f;
    for (int m = 0; m < 128; m += 4) {
        a0 += xr[m]     * d.Y[(size_t)(m)     * d.ldY + j];
        a1 += xr[m + 1] * d.Y[(size_t)(m + 1) * d.ldY + j];
        a2 += xr[m + 2] * d.Y[(size_t)(m + 2) * d.ldY + j];
        a3 += xr[m + 3] * d.Y[(size_t)(m + 3) * d.ldY + j];
    }
    d.Z[(size_t)i * d.ldZ + j] = (a0 + a1) + (a2 + a3);
}

/* ---- K4: phase 1, R=4 blocked: z <- A4 z + G u4; 16 iters ----
   512 thr: thread (g=t>>4 in 0..31 -> rows {g,g+32,g+64,g+96}; seg=t&15):
   A4 cols seg*8 (8 -> 32 regs), G cols seg*16 (16 -> 64 regs). */
__global__ __launch_bounds__(512, 4) void phase1_kernel(const float* __restrict__ u_,
                                                        const float* __restrict__ A4,
                                                        const float* __restrict__ G,
                                                        float* __restrict__ L) {
    int t = threadIdx.x;
    int g = t >> 4, seg = t & 15;
    int pair = blockIdx.x;          // pair = c*BATCH + b
    int c = pair >> 5, b = pair & 31;
    const float* urow = u_ + ((size_t)b * T_LEN + (size_t)c * KCH) * NU;

    float4 A4r[4][2], Gr[4][4];
#pragma unroll
    for (int r = 0; r < 4; ++r) {
        const float4* ap = (const float4*)(A4 + (size_t)(g + 32 * r) * NX + seg * 8);
        A4r[r][0] = ap[0]; A4r[r][1] = ap[1];
        const float4* gp = (const float4*)(G + (size_t)(g + 32 * r) * 256 + seg * 16);
        Gr[r][0] = gp[0]; Gr[r][1] = gp[1]; Gr[r][2] = gp[2]; Gr[r][3] = gp[3];
    }

    __shared__ __align__(16) float xs[2][192];   /* XP-padded 128 */
    __shared__ __align__(16) float us[2][320];   /* UP16-padded 256 */
    if (t < NX) xs[0][XP(t)] = 0.f;
    float up = (t < 256) ? urow[t] : 0.f;

    int buf = 0;
    for (int m = 0; m < 16; ++m) {
        if (t < 256) us[buf][UP16(t)] = up;
        if (t < 256 && m < 15) up = urow[(size_t)(m + 1) * 256 + t];
        __syncthreads();
        const float4* xq = (const float4*)&xs[buf][seg * 12];
        float4 xa = xq[0], xb = xq[1];
        const float4* uq = (const float4*)&us[buf][seg * 20];
        float acc0[4], acc1[4];
#pragma unroll
        for (int r = 0; r < 4; ++r) {
            acc0[r] = A4r[r][0].x * xa.x + A4r[r][0].y * xa.y
                    + A4r[r][0].z * xa.z + A4r[r][0].w * xa.w;
            acc1[r] = A4r[r][1].x * xb.x + A4r[r][1].y * xb.y
                    + A4r[r][1].z * xb.z + A4r[r][1].w * xb.w;
        }
#pragma unroll
        for (int q = 0; q < 4; ++q) {
            float4 uv = uq[q];
#pragma unroll
            for (int r = 0; r < 4; ++r) {
                float pr = Gr[r][q].x * uv.x + Gr[r][q].y * uv.y
                         + Gr[r][q].z * uv.z + Gr[r][q].w * uv.w;
                if (q & 1) acc1[r] += pr; else acc0[r] += pr;
            }
        }
        float acc[4];
#pragma unroll
        for (int r = 0; r < 4; ++r) acc[r] = acc0[r] + acc1[r];
#pragma unroll
        for (int d = 1; d <= 8; d <<= 1) {
#pragma unroll
            for (int r = 0; r < 4; ++r) acc[r] += __shfl_xor(acc[r], d);
        }
        if (seg == 0) {
            xs[buf ^ 1][XP(g)]      = acc[0];
            xs[buf ^ 1][XP(g + 32)] = acc[1];
            xs[buf ^ 1][XP(g + 64)] = acc[2];
            xs[buf ^ 1][XP(g + 96)] = acc[3];
        }
        buf ^= 1;
    }
    __syncthreads();
    if (t < NX) L[(size_t)pair * NX + t] = xs[buf][XP(t)];
}

/* ---- K5: phase 2 — chunk-level recurrence Xc[c+1] = A^64 Xc[c] + L[c] ---- */
__global__ __launch_bounds__(128) void phase2_kernel(const float* __restrict__ AK,
                                                     const float* __restrict__ L,
                                                     const float* __restrict__ x0,
                                                     float* __restrict__ Xc) {
    __shared__ float Ks[NX][NX + 1];
    __shared__ float xs[NX];
    int tid = threadIdx.x, b = blockIdx.x;
    for (int idx = tid; idx < NX * NX; idx += 128)
        Ks[idx >> 7][idx & 127] = AK[idx];
    float x = x0[tid];
    xs[tid] = x;
    Xc[(size_t)(0 * BATCH + b) * NX + tid] = x;
    __syncthreads();
    for (int c = 0; c < NC - 1; ++c) {
        float a0 = 0.f, a1 = 0.f, a2 = 0.f, a3 = 0.f;
        for (int j = 0; j < NX; j += 4) {
            a0 += Ks[tid][j]     * xs[j];
            a1 += Ks[tid][j + 1] * xs[j + 1];
            a2 += Ks[tid][j + 2] * xs[j + 2];
            a3 += Ks[tid][j + 3] * xs[j + 3];
        }
        float xn = (a0 + a1) + (a2 + a3) + L[((size_t)c * BATCH + b) * NX + tid];
        __syncthreads();
        xs[tid] = xn;
        Xc[((size_t)(c + 1) * BATCH + b) * NX + tid] = xn;
        __syncthreads();
    }
}

/* ---- K6: phase 3, R=2 role-split: 1024 thr ----
   waves 0-7 (t<512): state hop x_{t+2} = A2 x + [AB|B] u2 -> xs, XT[2m+2]
   waves 8-15:        emit x_{t+1} = A x + B u_t -> XT[2m+1]
   thread-within-half (g=t2>>4 -> rows {g+32r}; seg=t2&15). */
__global__ __launch_bounds__(1024, 4) void phase3_kernel(const float* __restrict__ u_,
                                                         const float* __restrict__ A,
                                                         const float* __restrict__ A2,
                                                         const float* __restrict__ G /* G2 = G+128, ld 256 */,
                                                         const float* __restrict__ Bm,
                                                         const float* __restrict__ Xc,
                                                         float* __restrict__ XT) {
    int t = threadIdx.x;
    int pair = blockIdx.x;
    int c = pair >> 5, b = pair & 31;
    const float* urow = u_ + ((size_t)b * T_LEN + (size_t)c * KCH) * NU;
    float* xtb = XT + (size_t)pair * KCH * NX;
    bool is_state = t < 512;
    int t2 = t & 511;
    int g = t2 >> 4, seg = t2 & 15;

    /* operators: state: A2 cols seg*8 (2 f4) + G2 cols seg*8 (2 f4)
                  emit:  A  cols seg*8 (2 f4) + B  cols seg*4 (1 f4) */
    float4 Op[4][4];
#pragma unroll
    for (int r = 0; r < 4; ++r) {
        int row = g + 32 * r;
        if (is_state) {
            const float4* ap = (const float4*)(A2 + (size_t)row * NX + seg * 8);
            Op[r][0] = ap[0]; Op[r][1] = ap[1];
            const float4* gp = (const float4*)(G + (size_t)row * 256 + 128 + seg * 8);
            Op[r][2] = gp[0]; Op[r][3] = gp[1];
        } else {
            const float4* ap = (const float4*)(A + (size_t)row * NX + seg * 8);
            Op[r][0] = ap[0]; Op[r][1] = ap[1];
            const float4* bp = (const float4*)(Bm + (size_t)row * NU + seg * 4);
            Op[r][2] = bp[0]; Op[r][3] = Op[r][2];
        }
    }

    __shared__ __align__(16) float xs[2][192];   /* XP-padded 128 */
    __shared__ __align__(16) float us[2][192];   /* XP-padded 128 (u2) */
    if (t < NX) {
        float v = Xc[(size_t)pair * NX + t];
        xs[0][XP(t)] = v;
        xtb[t] = v;
    }
    float up = (t < 128) ? urow[t] : 0.f;

    int buf = 0;
    for (int m = 0; m < 32; ++m) {
        if (t < 128) us[buf][XP(t)] = up;
        if (t < 128 && m < 31) up = urow[(size_t)(m + 1) * 128 + t];
        __syncthreads();
        const float4* xq = (const float4*)&xs[buf][seg * 12];
        float4 xa = xq[0], xb = xq[1];
        float acc[4];
        if (is_state) {
            const float4* uq = (const float4*)&us[buf][seg * 12];
            float4 ua = uq[0], ub = uq[1];
#pragma unroll
            for (int r = 0; r < 4; ++r) {
                float s0 = Op[r][0].x * xa.x + Op[r][0].y * xa.y
                         + Op[r][0].z * xa.z + Op[r][0].w * xa.w;
                float s1 = Op[r][1].x * xb.x + Op[r][1].y * xb.y
                         + Op[r][1].z * xb.z + Op[r][1].w * xb.w;
                s0 += Op[r][2].x * ua.x + Op[r][2].y * ua.y
                    + Op[r][2].z * ua.z + Op[r][2].w * ua.w;
                s1 += Op[r][3].x * ub.x + Op[r][3].y * ub.y
                    + Op[r][3].z * ub.z + Op[r][3].w * ub.w;
                acc[r] = s0 + s1;
            }
        } else {
            int ub0 = seg * 4;
            const float4* uq = (const float4*)&us[buf][ub0 + ((ub0 >> 3) << 2)];
            float4 ua = uq[0];
#pragma unroll
            for (int r = 0; r < 4; ++r) {
                float s0 = Op[r][0].x * xa.x + Op[r][0].y * xa.y
                         + Op[r][0].z * xa.z + Op[r][0].w * xa.w;
                float s1 = Op[r][1].x * xb.x + Op[r][1].y * xb.y
                         + Op[r][1].z * xb.z + Op[r][1].w * xb.w;
                s0 += Op[r][2].x * ua.x + Op[r][2].y * ua.y
                    + Op[r][2].z * ua.z + Op[r][2].w * ua.w;
                acc[r] = s0 + s1;
            }
        }
#pragma unroll
        for (int d = 1; d <= 8; d <<= 1) {
#pragma unroll
            for (int r = 0; r < 4; ++r) acc[r] += __shfl_xor(acc[r], d);
        }
        if (seg == 0) {
            if (is_state) {
                xs[buf ^ 1][XP(g)]      = acc[0];
                xs[buf ^ 1][XP(g + 32)] = acc[1];
                xs[buf ^ 1][XP(g + 64)] = acc[2];
                xs[buf ^ 1][XP(g + 96)] = acc[3];
                if (m < 31) {
                    float* xo = xtb + (size_t)(2 * m + 2) * NX;
                    xo[g] = acc[0]; xo[g + 32] = acc[1];
                    xo[g + 64] = acc[2]; xo[g + 96] = acc[3];
                }
            } else {
                float* xo = xtb + (size_t)(2 * m + 1) * NX;
                xo[g] = acc[0]; xo[g + 32] = acc[1];
                xo[g + 64] = acc[2]; xo[g + 96] = acc[3];
            }
        }
        buf ^= 1;
    }
}

/* ---- K7: y = XT * C^T, tiled GEMM, one (c,b) pair per block ---- */
__global__ __launch_bounds__(256) void yemit_kernel(const float* __restrict__ XT,
                                                    const float* __restrict__ C,
                                                    float* __restrict__ y) {
    __shared__ __align__(16) float xt[64][68];
    __shared__ float ct[64][65];
    int t = threadIdx.x;
    int pair = blockIdx.x;
    int b = pair & 31, c = pair >> 5;
    int rg = t & 15, pg = t >> 4;
    float acc[4][4];
#pragma unroll
    for (int i = 0; i < 4; ++i)
#pragma unroll
        for (int j = 0; j < 4; ++j) acc[i][j] = 0.f;
    const float* xbase = XT + (size_t)pair * KCH * NX;
    for (int kh = 0; kh < 2; ++kh) {
        __syncthreads();
        for (int idx = t; idx < 64 * 16; idx += 256) {
            int p = idx >> 4, kq = idx & 15;
            float4 v = *(const float4*)(xbase + (size_t)p * NX + kh * 64 + kq * 4);
            *(float4*)&xt[p][kq * 4] = v;
            float4 w = *(const float4*)(C + (size_t)p * NX + kh * 64 + kq * 4);
            ct[p][kq * 4]     = w.x;
            ct[p][kq * 4 + 1] = w.y;
            ct[p][kq * 4 + 2] = w.z;
            ct[p][kq * 4 + 3] = w.w;
        }
        __syncthreads();
#pragma unroll 4
        for (int kc = 0; kc < 16; ++kc) {
            float4 xv[4];
#pragma unroll
            for (int pp = 0; pp < 4; ++pp)
                xv[pp] = *(const float4*)&xt[pg * 4 + pp][kc * 4];
#pragma unroll
            for (int rr = 0; rr < 4; ++rr) {
                const float* cr = &ct[rg * 4 + rr][kc * 4];
                float c0 = cr[0], c1 = cr[1], c2 = cr[2], c3 = cr[3];
#pragma unroll
                for (int pp = 0; pp < 4; ++pp)
                    acc[pp][rr] += xv[pp].x * c0 + xv[pp].y * c1
                                 + xv[pp].z * c2 + xv[pp].w * c3;
            }
        }
    }
    float* ybase = y + ((size_t)b * T_LEN + (size_t)c * KCH) * NY;
#pragma unroll
    for (int pp = 0; pp < 4; ++pp) {
        float4 o;
        o.x = acc[pp][0]; o.y = acc[pp][1]; o.z = acc[pp][2]; o.w = acc[pp][3];
        *(float4*)(ybase + (size_t)(pg * 4 + pp) * NY + rg * 4) = o;
    }
}

/* ---- K6b (fallback, ws too small): serial phase3 with inline y-emit ---- */
__global__ __launch_bounds__(256) void phase3_fb_kernel(const float* __restrict__ u_,
                                                        const float* __restrict__ A,
                                                        const float* __restrict__ Bm,
                                                        const float* __restrict__ C,
                                                        const float* __restrict__ Xc,
                                                        float* __restrict__ y) {
    int t = threadIdx.x;
    int i = t >> 1, h = t & 1;
    int r = t >> 2, q = t & 3;
    int pair = blockIdx.x;
    int c = pair >> 5, b = pair & 31;
    const float* urow = u_ + ((size_t)b * T_LEN + (size_t)c * KCH) * NU;
    float* yrow = y + ((size_t)b * T_LEN + (size_t)c * KCH) * NY;
    float Ar[64];
    {
        const float4* Arow = (const float4*)(A + (size_t)i * NX + h * 64);
#pragma unroll
        for (int j4 = 0; j4 < 16; ++j4) {
            float4 v = Arow[j4];
            Ar[4 * j4] = v.x; Ar[4 * j4 + 1] = v.y; Ar[4 * j4 + 2] = v.z; Ar[4 * j4 + 3] = v.w;
        }
    }
    float Br[32];
    {
        const float4* Brow = (const float4*)(Bm + (size_t)i * NU + h * 32);
#pragma unroll
        for (int j4 = 0; j4 < 8; ++j4) {
            float4 v = Brow[j4];
            Br[4 * j4] = v.x; Br[4 * j4 + 1] = v.y; Br[4 * j4 + 2] = v.z; Br[4 * j4 + 3] = v.w;
        }
    }
    float Cr[32];
    {
        const float4* Crow = (const float4*)(C + (size_t)r * NX + q * 32);
#pragma unroll
        for (int j4 = 0; j4 < 8; ++j4) {
            float4 v = Crow[j4];
            Cr[4 * j4] = v.x; Cr[4 * j4 + 1] = v.y; Cr[4 * j4 + 2] = v.z; Cr[4 * j4 + 3] = v.w;
        }
    }
    __shared__ float xs[2][NX];
    __shared__ float us[2][NU];
    if (h == 0) xs[0][i] = Xc[(size_t)pair * NX + i];
    float up = (t < NU) ? urow[t] : 0.f;
    __syncthreads();
    {
        float c0 = 0.f, c1 = 0.f, c2 = 0.f, c3 = 0.f;
        const float* xp = &xs[0][q * 32];
#pragma unroll
        for (int j = 0; j < 32; j += 4) {
            c0 += Cr[j]     * xp[j];
            c1 += Cr[j + 1] * xp[j + 1];
            c2 += Cr[j + 2] * xp[j + 2];
            c3 += Cr[j + 3] * xp[j + 3];
        }
        float s = (c0 + c1) + (c2 + c3);
        s += __shfl_xor(s, 1);
        s += __shfl_xor(s, 2);
        if (q == 0) yrow[r] = s;
    }
    int buf = 0;
    for (int k = 1; k < KCH; ++k) {
        if (t < NU) us[buf][t] = up;
        if (k < KCH - 1 && t < NU) up = urow[(size_t)k * NU + t];
        __syncthreads();
        float a0 = 0.f, a1 = 0.f, a2 = 0.f, a3 = 0.f;
        const float* xp = &xs[buf][h * 64];
        const float* upp = &us[buf][h * 32];
#pragma unroll
        for (int j = 0; j < 64; j += 4) {
            a0 += Ar[j]     * xp[j];
            a1 += Ar[j + 1] * xp[j + 1];
            a2 += Ar[j + 2] * xp[j + 2];
            a3 += Ar[j + 3] * xp[j + 3];
        }
#pragma unroll
        for (int j = 0; j < 32; j += 4) {
            a0 += Br[j]     * upp[j];
            a1 += Br[j + 1] * upp[j + 1];
            a2 += Br[j + 2] * upp[j + 2];
            a3 += Br[j + 3] * upp[j + 3];
        }
        float a = (a0 + a1) + (a2 + a3);
        float s = a + __shfl_xor(a, 1);
        if (h == 0) xs[buf ^ 1][i] = s;
        __syncthreads();
        float c0 = 0.f, c1 = 0.f, c2 = 0.f, c3 = 0.f;
        const float* xcp = &xs[buf ^ 1][q * 32];
#pragma unroll
        for (int j = 0; j < 32; j += 4) {
            c0 += Cr[j]     * xcp[j];
            c1 += Cr[j + 1] * xcp[j + 1];
            c2 += Cr[j + 2] * xcp[j + 2];
            c3 += Cr[j + 3] * xcp[j + 3];
        }
        float sy = (c0 + c1) + (c2 + c3);
        sy += __shfl_xor(sy, 1);
        sy += __shfl_xor(sy, 2);
        if (q == 0) yrow[(size_t)k * NY + r] = sy;
        buf ^= 1;
    }
}

extern "C" void kernel_launch(void* const* d_in, const int* in_sizes, int n_in,
                              void* d_out, int out_size, void* d_ws, size_t ws_size,
                              hipStream_t stream) {
    const float* u_  = (const float*)d_in[0];
    const float* M   = (const float*)d_in[1];
    const float* Bm  = (const float*)d_in[2];
    const float* C   = (const float*)d_in[3];
    const float* x0  = (const float*)d_in[4];
    float* y = (float*)d_out;
    float* ws = (float*)d_ws;

    float* E  = ws + OFF_E;
    float* F  = ws + OFF_F;
    float* A  = ws + OFF_A;
    float* A2 = ws + OFF_E;   /* reuse */
    float* A4 = ws + OFF_F;   /* reuse */
    float* G  = ws + OFF_G;
    float* P0 = ws + OFF_P0;
    float* P1 = ws + OFF_P1;
    float* Xc = ws + OFF_XC;
    float* L  = ws + OFF_L;
    float* XT = ws + OFF_XT;

    ef_kernel<<<dim3(128, 2), 128, 0, stream>>>(M, E, F);
    solve_kernel<<<1, 256, 0, stream>>>(E, F, A);

    /* stage 1: A2 = A*A; G[:,128:192] = A*B (AB); G[:,192:256] = B */
    {
        MM3 mm;
        mm.d[0] = { A, A, A2,          128, NX, NX, NX  };
        mm.d[1] = { A, Bm, G + 128,     64, NX, NU, 256 };
        mm.d[2] = { Bm, nullptr, G + 192, 64, NU, 0, 256 };
        mm_batch_kernel<<<dim3(128, 3), 128, 0, stream>>>(mm);
    }
    /* stage 2: A4 = A2*A2; G[:,0:64] = A2*AB (A3B); G[:,64:128] = A2*B (A2B) */
    {
        MM3 mm;
        mm.d[0] = { A2, A2, A4,        128, NX, NX, NX  };
        mm.d[1] = { A2, G + 128, G,     64, NX, 256, 256 };
        mm.d[2] = { A2, Bm, G + 64,     64, NX, NU, 256 };
        mm_batch_kernel<<<dim3(128, 3), 128, 0, stream>>>(mm);
    }
    /* A64 by squaring: A8, A16, A32, A64 */
    matmul128_kernel<<<128, 128, 0, stream>>>(A4, A4, P0);
    matmul128_kernel<<<128, 128, 0, stream>>>(P0, P0, P1);
    matmul128_kernel<<<128, 128, 0, stream>>>(P1, P1, P0);
    matmul128_kernel<<<128, 128, 0, stream>>>(P0, P0, P1);

    phase1_kernel<<<NC * BATCH, 512, 0, stream>>>(u_, A4, G, L);
    phase2_kernel<<<BATCH, 128, 0, stream>>>(P1, L, x0, Xc);

    size_t need = ((size_t)OFF_XT + XT_FLOATS) * sizeof(float);
    if (ws_size >= need) {
        phase3_kernel<<<NC * BATCH, 1024, 0, stream>>>(u_, A, A2, G, Bm, Xc, XT);
        yemit_kernel<<<NC * BATCH, 256, 0, stream>>>(XT, C, y);
    } else {
        phase3_fb_kernel<<<NC * BATCH, 256, 0, stream>>>(u_, A, Bm, C, Xc, y);
    }
}

// Round 6
// 720.409 us; speedup vs baseline: 1.6977x; 1.6977x over previous
//
#include <hip/hip_runtime.h>

#define BATCH 32
#define T_LEN 4096
#define NU 64
#define NX 128
#define NY 64
#define KCH 64
#define NC (T_LEN / KCH)   /* 64 chunks */

/* workspace float offsets (E/F reused as A2/A4 after solve; XT overlaps L,
   which is dead after phase2) */
#define OFF_E   0            /* 16384; becomes A2 */
#define OFF_F   16384        /* 16384; becomes A4 */
#define OFF_A   32768        /* 16384 */
#define OFF_G   49152        /* 128x256 = 32768: [A3B|A2B|AB|B] */
#define OFF_P0  81920
#define OFF_P1  98304
#define OFF_XC  114688       /* 262144 */
#define OFF_L   376832       /* 262144 (XT overlaps; L dead after phase2) */
#define OFF_XT  376832
#define XT_FLOATS ((size_t)NC * BATCH * KCH * NX)   /* 16,777,216 floats */

/* padded LDS index helpers: break stride-8/stride-16 segment bank conflicts */
__device__ __forceinline__ int XP(int l)   { return l + ((l >> 3) << 2); }  /* +4 per 8 */
__device__ __forceinline__ int UP16(int l) { return l + ((l >> 4) << 2); }  /* +4 per 16 */

/* ---- K1: E = 0.5*(S22+S11)+1e-9 I, F = S21, from M (256x256) ---- */
__global__ void ef_kernel(const float* __restrict__ M, float* __restrict__ E,
                          float* __restrict__ F) {
    int i = blockIdx.x;      // row 0..127
    int j = threadIdx.x;     // col 0..127
    const float* Mi2 = M + (size_t)(128 + i) * 256;
    const float* Mj1 = M + (size_t)j * 256;
    if (blockIdx.y == 0) {
        const float* Mi1 = M + (size_t)i * 256;
        const float* Mj2 = M + (size_t)(128 + j) * 256;
        float s11 = 0.f, s22 = 0.f;
        for (int m = 0; m < 256; ++m) {
            s11 += Mi1[m] * Mj1[m];
            s22 += Mi2[m] * Mj2[m];
        }
        float e = 0.5f * (s11 + s22);
        if (i == j) e += 1e-9f;
        E[i * NX + j] = e;
    } else {
        float s21 = 0.f;
        for (int m = 0; m < 256; ++m) s21 += Mi2[m] * Mj1[m];
        F[i * NX + j] = s21;
    }
}

/* ---- K2: solve E * A = F via register-resident Gauss-Jordan ---- */
__global__ __launch_bounds__(256) void solve_kernel(const float* __restrict__ E,
                                                    const float* __restrict__ F,
                                                    float* __restrict__ A) {
    __shared__ __align__(16) float prow[2][256];
    __shared__ float mraw[2][128];
    __shared__ float pivarr[128];
    int t = threadIdx.x;
    int w = t >> 6, lane = t & 63;
    int h = w & 1, rb = w >> 1;
    int i = rb * 64 + lane;
    const float4* src = (const float4*)((h == 0 ? E : F) + (size_t)i * NX);
    float4 R[32];
#pragma unroll
    for (int j4 = 0; j4 < 32; ++j4) R[j4] = src[j4];
    if (i == 0) {
        float4* p4 = (float4*)&prow[0][h * 128];
#pragma unroll
        for (int j4 = 0; j4 < 32; ++j4) p4[j4] = R[j4];
    }
    if (h == 0) mraw[0][i] = R[0].x;
    __syncthreads();

    for (int k = 0; k < NX; ++k) {
        int cur = k & 1, nxt = cur ^ 1;
        float piv = prow[cur][k];
        if (h == 0 && i == k) pivarr[k] = piv;
        float invp = 1.0f / piv;
        float m = mraw[cur][i] * invp;
        m = (i == k) ? 0.0f : m;
        const float4* p4 = (const float4*)&prow[cur][h * 128];
#pragma unroll
        for (int j4 = 0; j4 < 32; ++j4) {
            float4 p = p4[j4];
            R[j4].x -= m * p.x;
            R[j4].y -= m * p.y;
            R[j4].z -= m * p.z;
            R[j4].w -= m * p.w;
        }
        if (k < NX - 1) {
            if (i == k + 1) {
                float4* q4 = (float4*)&prow[nxt][h * 128];
#pragma unroll
                for (int j4 = 0; j4 < 32; ++j4) q4[j4] = R[j4];
            }
            if (h == 0) {
                int kq = (k + 1) >> 2, kr = (k + 1) & 3;
                float4 vv = R[0];
#pragma unroll
                for (int j4 = 1; j4 < 32; ++j4) if (j4 == kq) vv = R[j4];
                float val = (kr == 0) ? vv.x : (kr == 1) ? vv.y
                          : (kr == 2) ? vv.z : vv.w;
                mraw[nxt][i] = val;
            }
        }
        __syncthreads();
    }

    if (h == 1) {
        float s = 1.0f / pivarr[i];
        float4* dst = (float4*)(A + (size_t)i * NX);
#pragma unroll
        for (int j4 = 0; j4 < 32; ++j4) {
            float4 v = R[j4];
            v.x *= s; v.y *= s; v.z *= s; v.w *= s;
            dst[j4] = v;
        }
    }
}

/* ---- K3: Z = X*Y, 128x128 fp32 (squarings) ---- */
__global__ void matmul128_kernel(const float* __restrict__ X,
                                 const float* __restrict__ Y,
                                 float* __restrict__ Z) {
    int i = blockIdx.x, j = threadIdx.x;
    float a0 = 0.f, a1 = 0.f, a2 = 0.f, a3 = 0.f;
    for (int m = 0; m < NX; m += 4) {
        a0 += X[i * NX + m]     * Y[(m)     * NX + j];
        a1 += X[i * NX + m + 1] * Y[(m + 1) * NX + j];
        a2 += X[i * NX + m + 2] * Y[(m + 2) * NX + j];
        a3 += X[i * NX + m + 3] * Y[(m + 3) * NX + j];
    }
    Z[i * NX + j] = (a0 + a1) + (a2 + a3);
}

/* ---- K3b: batched small matmuls Z(128xN) = X(128x128)*Y(128xN); Y=null => copy ---- */
struct MMDesc { const float* X; const float* Y; float* Z; int N; int ldX; int ldY; int ldZ; };
struct MM3 { MMDesc d[3]; };
__global__ __launch_bounds__(128) void mm_batch_kernel(MM3 mm) {
    MMDesc d = mm.d[blockIdx.y];
    int i = blockIdx.x, j = threadIdx.x;
    if (j >= d.N) return;
    if (d.Y == nullptr) {
        d.Z[(size_t)i * d.ldZ + j] = d.X[(size_t)i * d.ldX + j];
        return;
    }
    const float* xr = d.X + (size_t)i * d.ldX;
    float a0 = 0.f, a1 = 0.f, a2 = 0.f, a3 = 0.f;
    for (int m = 0; m < 128; m += 4) {
        a0 += xr[m]     * d.Y[(size_t)(m)     * d.ldY + j];
        a1 += xr[m + 1] * d.Y[(size_t)(m + 1) * d.ldY + j];
        a2 += xr[m + 2] * d.Y[(size_t)(m + 2) * d.ldY + j];
        a3 += xr[m + 3] * d.Y[(size_t)(m + 3) * d.ldY + j];
    }
    d.Z[(size_t)i * d.ldZ + j] = (a0 + a1) + (a2 + a3);
}

/* ---- K4: phase 1, R=4 blocked: z <- A4 z + G u4; 16 iters ---- */
__global__ __launch_bounds__(512, 4) void phase1_kernel(const float* __restrict__ u_,
                                                        const float* __restrict__ A4,
                                                        const float* __restrict__ G,
                                                        float* __restrict__ L) {
    int t = threadIdx.x;
    int g = t >> 4, seg = t & 15;
    int pair = blockIdx.x;          // pair = c*BATCH + b
    int c = pair >> 5, b = pair & 31;
    const float* urow = u_ + ((size_t)b * T_LEN + (size_t)c * KCH) * NU;

    float4 A4r[4][2], Gr[4][4];
#pragma unroll
    for (int r = 0; r < 4; ++r) {
        const float4* ap = (const float4*)(A4 + (size_t)(g + 32 * r) * NX + seg * 8);
        A4r[r][0] = ap[0]; A4r[r][1] = ap[1];
        const float4* gp = (const float4*)(G + (size_t)(g + 32 * r) * 256 + seg * 16);
        Gr[r][0] = gp[0]; Gr[r][1] = gp[1]; Gr[r][2] = gp[2]; Gr[r][3] = gp[3];
    }

    __shared__ __align__(16) float xs[2][192];   /* XP-padded 128 */
    __shared__ __align__(16) float us[2][320];   /* UP16-padded 256 */
    if (t < NX) xs[0][XP(t)] = 0.f;
    float up = (t < 256) ? urow[t] : 0.f;

    int buf = 0;
    for (int m = 0; m < 16; ++m) {
        if (t < 256) us[buf][UP16(t)] = up;
        if (t < 256 && m < 15) up = urow[(size_t)(m + 1) * 256 + t];
        __syncthreads();
        const float4* xq = (const float4*)&xs[buf][seg * 12];
        float4 xa = xq[0], xb = xq[1];
        const float4* uq = (const float4*)&us[buf][seg * 20];
        float acc0[4], acc1[4];
#pragma unroll
        for (int r = 0; r < 4; ++r) {
            acc0[r] = A4r[r][0].x * xa.x + A4r[r][0].y * xa.y
                    + A4r[r][0].z * xa.z + A4r[r][0].w * xa.w;
            acc1[r] = A4r[r][1].x * xb.x + A4r[r][1].y * xb.y
                    + A4r[r][1].z * xb.z + A4r[r][1].w * xb.w;
        }
#pragma unroll
        for (int q = 0; q < 4; ++q) {
            float4 uv = uq[q];
#pragma unroll
            for (int r = 0; r < 4; ++r) {
                float pr = Gr[r][q].x * uv.x + Gr[r][q].y * uv.y
                         + Gr[r][q].z * uv.z + Gr[r][q].w * uv.w;
                if (q & 1) acc1[r] += pr; else acc0[r] += pr;
            }
        }
        float acc[4];
#pragma unroll
        for (int r = 0; r < 4; ++r) acc[r] = acc0[r] + acc1[r];
#pragma unroll
        for (int d = 1; d <= 8; d <<= 1) {
#pragma unroll
            for (int r = 0; r < 4; ++r) acc[r] += __shfl_xor(acc[r], d);
        }
        if (seg == 0) {
            xs[buf ^ 1][XP(g)]      = acc[0];
            xs[buf ^ 1][XP(g + 32)] = acc[1];
            xs[buf ^ 1][XP(g + 64)] = acc[2];
            xs[buf ^ 1][XP(g + 96)] = acc[3];
        }
        buf ^= 1;
    }
    __syncthreads();
    if (t < NX) L[(size_t)pair * NX + t] = xs[buf][XP(t)];
}

/* ---- K5: phase 2 — chunk-level recurrence Xc[c+1] = A^64 Xc[c] + L[c] ---- */
__global__ __launch_bounds__(128) void phase2_kernel(const float* __restrict__ AK,
                                                     const float* __restrict__ L,
                                                     const float* __restrict__ x0,
                                                     float* __restrict__ Xc) {
    __shared__ float Ks[NX][NX + 1];
    __shared__ float xs[NX];
    int tid = threadIdx.x, b = blockIdx.x;
    for (int idx = tid; idx < NX * NX; idx += 128)
        Ks[idx >> 7][idx & 127] = AK[idx];
    float x = x0[tid];
    xs[tid] = x;
    Xc[(size_t)(0 * BATCH + b) * NX + tid] = x;
    __syncthreads();
    for (int c = 0; c < NC - 1; ++c) {
        float a0 = 0.f, a1 = 0.f, a2 = 0.f, a3 = 0.f;
        for (int j = 0; j < NX; j += 4) {
            a0 += Ks[tid][j]     * xs[j];
            a1 += Ks[tid][j + 1] * xs[j + 1];
            a2 += Ks[tid][j + 2] * xs[j + 2];
            a3 += Ks[tid][j + 3] * xs[j + 3];
        }
        float xn = (a0 + a1) + (a2 + a3) + L[((size_t)c * BATCH + b) * NX + tid];
        __syncthreads();
        xs[tid] = xn;
        Xc[((size_t)(c + 1) * BATCH + b) * NX + tid] = xn;
        __syncthreads();
    }
}

/* ---- K6: phase 3, R=2 role-split, COALESCED XT writes via LDS staging ----
   waves 0-7 (t<512): state hop x_{t+2} = A2 x + [AB|B] u2 -> xs[buf^1]
   waves 8-15:        emit x_{t+1} = A x + B u_t -> xe[buf]
   After each barrier, t<128 flushes rows 2m (from xs[buf]) and 2m-1
   (from xe[buf^1]) as contiguous 512B stores. One barrier per iter. */
__global__ __launch_bounds__(1024, 4) void phase3_kernel(const float* __restrict__ u_,
                                                         const float* __restrict__ A,
                                                         const float* __restrict__ A2,
                                                         const float* __restrict__ G /* G2 = G+128, ld 256 */,
                                                         const float* __restrict__ Bm,
                                                         const float* __restrict__ Xc,
                                                         float* __restrict__ XT) {
    int t = threadIdx.x;
    int pair = blockIdx.x;
    int c = pair >> 5, b = pair & 31;
    const float* urow = u_ + ((size_t)b * T_LEN + (size_t)c * KCH) * NU;
    float* xtb = XT + (size_t)pair * KCH * NX;
    bool is_state = t < 512;
    int t2 = t & 511;
    int g = t2 >> 4, seg = t2 & 15;

    /* operators: state: A2 cols seg*8 (2 f4) + G2 cols seg*8 (2 f4)
                  emit:  A  cols seg*8 (2 f4) + B  cols seg*4 (1 f4) */
    float4 Op[4][4];
#pragma unroll
    for (int r = 0; r < 4; ++r) {
        int row = g + 32 * r;
        if (is_state) {
            const float4* ap = (const float4*)(A2 + (size_t)row * NX + seg * 8);
            Op[r][0] = ap[0]; Op[r][1] = ap[1];
            const float4* gp = (const float4*)(G + (size_t)row * 256 + 128 + seg * 8);
            Op[r][2] = gp[0]; Op[r][3] = gp[1];
        } else {
            const float4* ap = (const float4*)(A + (size_t)row * NX + seg * 8);
            Op[r][0] = ap[0]; Op[r][1] = ap[1];
            const float4* bp = (const float4*)(Bm + (size_t)row * NU + seg * 4);
            Op[r][2] = bp[0]; Op[r][3] = Op[r][2];
        }
    }

    __shared__ __align__(16) float xs[2][192];   /* XP-padded 128: x_{2m} */
    __shared__ __align__(16) float us[2][192];   /* XP-padded 128: u2 */
    __shared__ __align__(16) float xe[2][192];   /* XP-padded 128: emit x_{2m+1} */
    if (t < NX) xs[0][XP(t)] = Xc[(size_t)pair * NX + t];
    float up = (t < 128) ? urow[t] : 0.f;

    int buf = 0;
    for (int m = 0; m < 32; ++m) {
        if (t < 128) us[buf][XP(t)] = up;
        if (t < 128 && m < 31) up = urow[(size_t)(m + 1) * 128 + t];
        __syncthreads();
        /* coalesced flush of completed rows (producers wrote pre-barrier) */
        if (t < 128) {
            xtb[(size_t)(2 * m) * NX + t] = xs[buf][XP(t)];
            if (m > 0) xtb[(size_t)(2 * m - 1) * NX + t] = xe[buf ^ 1][XP(t)];
        }
        const float4* xq = (const float4*)&xs[buf][seg * 12];
        float4 xa = xq[0], xb = xq[1];
        float acc[4];
        if (is_state) {
            const float4* uq = (const float4*)&us[buf][seg * 12];
            float4 ua = uq[0], ub = uq[1];
#pragma unroll
            for (int r = 0; r < 4; ++r) {
                float s0 = Op[r][0].x * xa.x + Op[r][0].y * xa.y
                         + Op[r][0].z * xa.z + Op[r][0].w * xa.w;
                float s1 = Op[r][1].x * xb.x + Op[r][1].y * xb.y
                         + Op[r][1].z * xb.z + Op[r][1].w * xb.w;
                s0 += Op[r][2].x * ua.x + Op[r][2].y * ua.y
                    + Op[r][2].z * ua.z + Op[r][2].w * ua.w;
                s1 += Op[r][3].x * ub.x + Op[r][3].y * ub.y
                    + Op[r][3].z * ub.z + Op[r][3].w * ub.w;
                acc[r] = s0 + s1;
            }
        } else {
            int ub0 = seg * 4;
            const float4* uq = (const float4*)&us[buf][ub0 + ((ub0 >> 3) << 2)];
            float4 ua = uq[0];
#pragma unroll
            for (int r = 0; r < 4; ++r) {
                float s0 = Op[r][0].x * xa.x + Op[r][0].y * xa.y
                         + Op[r][0].z * xa.z + Op[r][0].w * xa.w;
                float s1 = Op[r][1].x * xb.x + Op[r][1].y * xb.y
                         + Op[r][1].z * xb.z + Op[r][1].w * xb.w;
                s0 += Op[r][2].x * ua.x + Op[r][2].y * ua.y
                    + Op[r][2].z * ua.z + Op[r][2].w * ua.w;
                acc[r] = s0 + s1;
            }
        }
#pragma unroll
        for (int d = 1; d <= 8; d <<= 1) {
#pragma unroll
            for (int r = 0; r < 4; ++r) acc[r] += __shfl_xor(acc[r], d);
        }
        if (seg == 0) {
            if (is_state) {
                xs[buf ^ 1][XP(g)]      = acc[0];
                xs[buf ^ 1][XP(g + 32)] = acc[1];
                xs[buf ^ 1][XP(g + 64)] = acc[2];
                xs[buf ^ 1][XP(g + 96)] = acc[3];
            } else {
                xe[buf][XP(g)]      = acc[0];
                xe[buf][XP(g + 32)] = acc[1];
                xe[buf][XP(g + 64)] = acc[2];
                xe[buf][XP(g + 96)] = acc[3];
            }
        }
        buf ^= 1;
    }
    __syncthreads();
    if (t < 128) xtb[(size_t)63 * NX + t] = xe[buf ^ 1][XP(t)];
}

/* ---- K7: y = XT * C^T, tiled GEMM, one (c,b) pair per block ---- */
__global__ __launch_bounds__(256) void yemit_kernel(const float* __restrict__ XT,
                                                    const float* __restrict__ C,
                                                    float* __restrict__ y) {
    __shared__ __align__(16) float xt[64][68];
    __shared__ float ct[64][65];
    int t = threadIdx.x;
    int pair = blockIdx.x;
    int b = pair & 31, c = pair >> 5;
    int rg = t & 15, pg = t >> 4;
    float acc[4][4];
#pragma unroll
    for (int i = 0; i < 4; ++i)
#pragma unroll
        for (int j = 0; j < 4; ++j) acc[i][j] = 0.f;
    const float* xbase = XT + (size_t)pair * KCH * NX;
    for (int kh = 0; kh < 2; ++kh) {
        __syncthreads();
        for (int idx = t; idx < 64 * 16; idx += 256) {
            int p = idx >> 4, kq = idx & 15;
            float4 v = *(const float4*)(xbase + (size_t)p * NX + kh * 64 + kq * 4);
            *(float4*)&xt[p][kq * 4] = v;
            float4 w = *(const float4*)(C + (size_t)p * NX + kh * 64 + kq * 4);
            ct[p][kq * 4]     = w.x;
            ct[p][kq * 4 + 1] = w.y;
            ct[p][kq * 4 + 2] = w.z;
            ct[p][kq * 4 + 3] = w.w;
        }
        __syncthreads();
#pragma unroll 4
        for (int kc = 0; kc < 16; ++kc) {
            float4 xv[4];
#pragma unroll
            for (int pp = 0; pp < 4; ++pp)
                xv[pp] = *(const float4*)&xt[pg * 4 + pp][kc * 4];
#pragma unroll
            for (int rr = 0; rr < 4; ++rr) {
                const float* cr = &ct[rg * 4 + rr][kc * 4];
                float c0 = cr[0], c1 = cr[1], c2 = cr[2], c3 = cr[3];
#pragma unroll
                for (int pp = 0; pp < 4; ++pp)
                    acc[pp][rr] += xv[pp].x * c0 + xv[pp].y * c1
                                 + xv[pp].z * c2 + xv[pp].w * c3;
            }
        }
    }
    float* ybase = y + ((size_t)b * T_LEN + (size_t)c * KCH) * NY;
#pragma unroll
    for (int pp = 0; pp < 4; ++pp) {
        float4 o;
        o.x = acc[pp][0]; o.y = acc[pp][1]; o.z = acc[pp][2]; o.w = acc[pp][3];
        *(float4*)(ybase + (size_t)(pg * 4 + pp) * NY + rg * 4) = o;
    }
}

/* ---- K6b (fallback, ws too small): serial phase3 with inline y-emit ---- */
__global__ __launch_bounds__(256) void phase3_fb_kernel(const float* __restrict__ u_,
                                                        const float* __restrict__ A,
                                                        const float* __restrict__ Bm,
                                                        const float* __restrict__ C,
                                                        const float* __restrict__ Xc,
                                                        float* __restrict__ y) {
    int t = threadIdx.x;
    int i = t >> 1, h = t & 1;
    int r = t >> 2, q = t & 3;
    int pair = blockIdx.x;
    int c = pair >> 5, b = pair & 31;
    const float* urow = u_ + ((size_t)b * T_LEN + (size_t)c * KCH) * NU;
    float* yrow = y + ((size_t)b * T_LEN + (size_t)c * KCH) * NY;
    float Ar[64];
    {
        const float4* Arow = (const float4*)(A + (size_t)i * NX + h * 64);
#pragma unroll
        for (int j4 = 0; j4 < 16; ++j4) {
            float4 v = Arow[j4];
            Ar[4 * j4] = v.x; Ar[4 * j4 + 1] = v.y; Ar[4 * j4 + 2] = v.z; Ar[4 * j4 + 3] = v.w;
        }
    }
    float Br[32];
    {
        const float4* Brow = (const float4*)(Bm + (size_t)i * NU + h * 32);
#pragma unroll
        for (int j4 = 0; j4 < 8; ++j4) {
            float4 v = Brow[j4];
            Br[4 * j4] = v.x; Br[4 * j4 + 1] = v.y; Br[4 * j4 + 2] = v.z; Br[4 * j4 + 3] = v.w;
        }
    }
    float Cr[32];
    {
        const float4* Crow = (const float4*)(C + (size_t)r * NX + q * 32);
#pragma unroll
        for (int j4 = 0; j4 < 8; ++j4) {
            float4 v = Crow[j4];
            Cr[4 * j4] = v.x; Cr[4 * j4 + 1] = v.y; Cr[4 * j4 + 2] = v.z; Cr[4 * j4 + 3] = v.w;
        }
    }
    __shared__ float xs[2][NX];
    __shared__ float us[2][NU];
    if (h == 0) xs[0][i] = Xc[(size_t)pair * NX + i];
    float up = (t < NU) ? urow[t] : 0.f;
    __syncthreads();
    {
        float c0 = 0.f, c1 = 0.f, c2 = 0.f, c3 = 0.f;
        const float* xp = &xs[0][q * 32];
#pragma unroll
        for (int j = 0; j < 32; j += 4) {
            c0 += Cr[j]     * xp[j];
            c1 += Cr[j + 1] * xp[j + 1];
            c2 += Cr[j + 2] * xp[j + 2];
            c3 += Cr[j + 3] * xp[j + 3];
        }
        float s = (c0 + c1) + (c2 + c3);
        s += __shfl_xor(s, 1);
        s += __shfl_xor(s, 2);
        if (q == 0) yrow[r] = s;
    }
    int buf = 0;
    for (int k = 1; k < KCH; ++k) {
        if (t < NU) us[buf][t] = up;
        if (k < KCH - 1 && t < NU) up = urow[(size_t)k * NU + t];
        __syncthreads();
        float a0 = 0.f, a1 = 0.f, a2 = 0.f, a3 = 0.f;
        const float* xp = &xs[buf][h * 64];
        const float* upp = &us[buf][h * 32];
#pragma unroll
        for (int j = 0; j < 64; j += 4) {
            a0 += Ar[j]     * xp[j];
            a1 += Ar[j + 1] * xp[j + 1];
            a2 += Ar[j + 2] * xp[j + 2];
            a3 += Ar[j + 3] * xp[j + 3];
        }
#pragma unroll
        for (int j = 0; j < 32; j += 4) {
            a0 += Br[j]     * upp[j];
            a1 += Br[j + 1] * upp[j + 1];
            a2 += Br[j + 2] * upp[j + 2];
            a3 += Br[j + 3] * upp[j + 3];
        }
        float a = (a0 + a1) + (a2 + a3);
        float s = a + __shfl_xor(a, 1);
        if (h == 0) xs[buf ^ 1][i] = s;
        __syncthreads();
        float c0 = 0.f, c1 = 0.f, c2 = 0.f, c3 = 0.f;
        const float* xcp = &xs[buf ^ 1][q * 32];
#pragma unroll
        for (int j = 0; j < 32; j += 4) {
            c0 += Cr[j]     * xcp[j];
            c1 += Cr[j + 1] * xcp[j + 1];
            c2 += Cr[j + 2] * xcp[j + 2];
            c3 += Cr[j + 3] * xcp[j + 3];
        }
        float sy = (c0 + c1) + (c2 + c3);
        sy += __shfl_xor(sy, 1);
        sy += __shfl_xor(sy, 2);
        if (q == 0) yrow[(size_t)k * NY + r] = sy;
        buf ^= 1;
    }
}

extern "C" void kernel_launch(void* const* d_in, const int* in_sizes, int n_in,
                              void* d_out, int out_size, void* d_ws, size_t ws_size,
                              hipStream_t stream) {
    const float* u_  = (const float*)d_in[0];
    const float* M   = (const float*)d_in[1];
    const float* Bm  = (const float*)d_in[2];
    const float* C   = (const float*)d_in[3];
    const float* x0  = (const float*)d_in[4];
    float* y = (float*)d_out;
    float* ws = (float*)d_ws;

    float* E  = ws + OFF_E;
    float* F  = ws + OFF_F;
    float* A  = ws + OFF_A;
    float* A2 = ws + OFF_E;   /* reuse */
    float* A4 = ws + OFF_F;   /* reuse */
    float* G  = ws + OFF_G;
    float* P0 = ws + OFF_P0;
    float* P1 = ws + OFF_P1;
    float* Xc = ws + OFF_XC;
    float* L  = ws + OFF_L;
    float* XT = ws + OFF_XT;

    ef_kernel<<<dim3(128, 2), 128, 0, stream>>>(M, E, F);
    solve_kernel<<<1, 256, 0, stream>>>(E, F, A);

    /* stage 1: A2 = A*A; G[:,128:192] = A*B (AB); G[:,192:256] = B */
    {
        MM3 mm;
        mm.d[0] = { A, A, A2,          128, NX, NX, NX  };
        mm.d[1] = { A, Bm, G + 128,     64, NX, NU, 256 };
        mm.d[2] = { Bm, nullptr, G + 192, 64, NU, 0, 256 };
        mm_batch_kernel<<<dim3(128, 3), 128, 0, stream>>>(mm);
    }
    /* stage 2: A4 = A2*A2; G[:,0:64] = A2*AB (A3B); G[:,64:128] = A2*B (A2B) */
    {
        MM3 mm;
        mm.d[0] = { A2, A2, A4,        128, NX, NX, NX  };
        mm.d[1] = { A2, G + 128, G,     64, NX, 256, 256 };
        mm.d[2] = { A2, Bm, G + 64,     64, NX, NU, 256 };
        mm_batch_kernel<<<dim3(128, 3), 128, 0, stream>>>(mm);
    }
    /* A64 by squaring: A8, A16, A32, A64 */
    matmul128_kernel<<<128, 128, 0, stream>>>(A4, A4, P0);
    matmul128_kernel<<<128, 128, 0, stream>>>(P0, P0, P1);
    matmul128_kernel<<<128, 128, 0, stream>>>(P1, P1, P0);
    matmul128_kernel<<<128, 128, 0, stream>>>(P0, P0, P1);

    phase1_kernel<<<NC * BATCH, 512, 0, stream>>>(u_, A4, G, L);
    phase2_kernel<<<BATCH, 128, 0, stream>>>(P1, L, x0, Xc);

    size_t need = ((size_t)OFF_XT + XT_FLOATS) * sizeof(float);
    if (ws_size >= need) {
        phase3_kernel<<<NC * BATCH, 1024, 0, stream>>>(u_, A, A2, G, Bm, Xc, XT);
        yemit_kernel<<<NC * BATCH, 256, 0, stream>>>(XT, C, y);
    } else {
        phase3_fb_kernel<<<NC * BATCH, 256, 0, stream>>>(u_, A, Bm, C, Xc, y);
    }
}

// Round 7
// 543.283 us; speedup vs baseline: 2.2512x; 1.3260x over previous
//
#include <hip/hip_runtime.h>

#define BATCH 32
#define T_LEN 4096
#define NU 64
#define NX 128
#define NY 64
#define KCH 64
#define NC (T_LEN / KCH)   /* 64 chunks */

/* workspace float offsets */
#define OFF_E    0            /* 16384; becomes A2 */
#define OFF_F    16384        /* 16384; becomes A4 */
#define OFF_A    32768        /* 16384 */
#define OFF_G    49152        /* 128x256: [A3B|A2B|AB|B] */
#define OFF_P0   81920        /* 16384 squaring scratch */
#define OFF_P1   98304        /* 16384 squaring scratch (final A64) */
#define OFF_D    114688       /* 24576: D1,D2,D3 (64x128 each) */
#define OFF_P    139264       /* 12288: P0,P1,P2 (64x64 each) */
#define OFF_WT   151552       /* 40960 floats = 81920 bf16: WT[256][320] */
#define OFF_XC   192512       /* 262144 */
#define OFF_L    454656       /* 262144 */
#define OFF_X4   716800       /* X4 bf16: 32768x128 = 4194304 us = 2097152 f */
#define OFF_UB   2813952      /* u bf16: 8388608 us = 4194304 f */
#define WS_NEED_FLOATS (2813952 + 4194304)

/* padded LDS index helpers */
__device__ __forceinline__ int XP(int l)   { return l + ((l >> 3) << 2); }
__device__ __forceinline__ int UP16(int l) { return l + ((l >> 4) << 2); }

__device__ __forceinline__ unsigned short f2bf(float f) {
    unsigned int x = __float_as_uint(f);
    unsigned int r = (x + 0x7FFFu + ((x >> 16) & 1u)) >> 16;
    return (unsigned short)r;
}

typedef __attribute__((ext_vector_type(8))) short bf16x8;
typedef __attribute__((ext_vector_type(4))) float f32x4;

/* ---- K1: E = 0.5*(S22+S11)+1e-9 I, F = S21, from M (256x256) ---- */
__global__ void ef_kernel(const float* __restrict__ M, float* __restrict__ E,
                          float* __restrict__ F) {
    int i = blockIdx.x;
    int j = threadIdx.x;
    const float* Mi2 = M + (size_t)(128 + i) * 256;
    const float* Mj1 = M + (size_t)j * 256;
    if (blockIdx.y == 0) {
        const float* Mi1 = M + (size_t)i * 256;
        const float* Mj2 = M + (size_t)(128 + j) * 256;
        float s11 = 0.f, s22 = 0.f;
        for (int m = 0; m < 256; ++m) {
            s11 += Mi1[m] * Mj1[m];
            s22 += Mi2[m] * Mj2[m];
        }
        float e = 0.5f * (s11 + s22);
        if (i == j) e += 1e-9f;
        E[i * NX + j] = e;
    } else {
        float s21 = 0.f;
        for (int m = 0; m < 256; ++m) s21 += Mi2[m] * Mj1[m];
        F[i * NX + j] = s21;
    }
}

/* ---- K2: solve E * A = F via register-resident Gauss-Jordan ---- */
__global__ __launch_bounds__(256) void solve_kernel(const float* __restrict__ E,
                                                    const float* __restrict__ F,
                                                    float* __restrict__ A) {
    __shared__ __align__(16) float prow[2][256];
    __shared__ float mraw[2][128];
    __shared__ float pivarr[128];
    int t = threadIdx.x;
    int w = t >> 6, lane = t & 63;
    int h = w & 1, rb = w >> 1;
    int i = rb * 64 + lane;
    const float4* src = (const float4*)((h == 0 ? E : F) + (size_t)i * NX);
    float4 R[32];
#pragma unroll
    for (int j4 = 0; j4 < 32; ++j4) R[j4] = src[j4];
    if (i == 0) {
        float4* p4 = (float4*)&prow[0][h * 128];
#pragma unroll
        for (int j4 = 0; j4 < 32; ++j4) p4[j4] = R[j4];
    }
    if (h == 0) mraw[0][i] = R[0].x;
    __syncthreads();

    for (int k = 0; k < NX; ++k) {
        int cur = k & 1, nxt = cur ^ 1;
        float piv = prow[cur][k];
        if (h == 0 && i == k) pivarr[k] = piv;
        float invp = 1.0f / piv;
        float m = mraw[cur][i] * invp;
        m = (i == k) ? 0.0f : m;
        const float4* p4 = (const float4*)&prow[cur][h * 128];
#pragma unroll
        for (int j4 = 0; j4 < 32; ++j4) {
            float4 p = p4[j4];
            R[j4].x -= m * p.x;
            R[j4].y -= m * p.y;
            R[j4].z -= m * p.z;
            R[j4].w -= m * p.w;
        }
        if (k < NX - 1) {
            if (i == k + 1) {
                float4* q4 = (float4*)&prow[nxt][h * 128];
#pragma unroll
                for (int j4 = 0; j4 < 32; ++j4) q4[j4] = R[j4];
            }
            if (h == 0) {
                int kq = (k + 1) >> 2, kr = (k + 1) & 3;
                float4 vv = R[0];
#pragma unroll
                for (int j4 = 1; j4 < 32; ++j4) if (j4 == kq) vv = R[j4];
                float val = (kr == 0) ? vv.x : (kr == 1) ? vv.y
                          : (kr == 2) ? vv.z : vv.w;
                mraw[nxt][i] = val;
            }
        }
        __syncthreads();
    }

    if (h == 1) {
        float s = 1.0f / pivarr[i];
        float4* dst = (float4*)(A + (size_t)i * NX);
#pragma unroll
        for (int j4 = 0; j4 < 32; ++j4) {
            float4 v = R[j4];
            v.x *= s; v.y *= s; v.z *= s; v.w *= s;
            dst[j4] = v;
        }
    }
}

/* ---- K3: Z = X*Y, 128x128 fp32 (squarings) ---- */
__global__ void matmul128_kernel(const float* __restrict__ X,
                                 const float* __restrict__ Y,
                                 float* __restrict__ Z) {
    int i = blockIdx.x, j = threadIdx.x;
    float a0 = 0.f, a1 = 0.f, a2 = 0.f, a3 = 0.f;
    for (int m = 0; m < NX; m += 4) {
        a0 += X[i * NX + m]     * Y[(m)     * NX + j];
        a1 += X[i * NX + m + 1] * Y[(m + 1) * NX + j];
        a2 += X[i * NX + m + 2] * Y[(m + 2) * NX + j];
        a3 += X[i * NX + m + 3] * Y[(m + 3) * NX + j];
    }
    Z[i * NX + j] = (a0 + a1) + (a2 + a3);
}

/* ---- K3b: batched small matmuls; Y=null => copy; Z=null => skip ---- */
struct MMDesc { const float* X; const float* Y; float* Z; int N; int ldX; int ldY; int ldZ; int Mrows; };
struct MM3 { MMDesc d[3]; };
__global__ __launch_bounds__(128) void mm_batch_kernel(MM3 mm) {
    MMDesc d = mm.d[blockIdx.y];
    int i = blockIdx.x, j = threadIdx.x;
    if (d.Z == nullptr || i >= d.Mrows || j >= d.N) return;
    if (d.Y == nullptr) {
        d.Z[(size_t)i * d.ldZ + j] = d.X[(size_t)i * d.ldX + j];
        return;
    }
    const float* xr = d.X + (size_t)i * d.ldX;
    float a0 = 0.f, a1 = 0.f, a2 = 0.f, a3 = 0.f;
    for (int m = 0; m < 128; m += 4) {
        a0 += xr[m]     * d.Y[(size_t)(m)     * d.ldY + j];
        a1 += xr[m + 1] * d.Y[(size_t)(m + 1) * d.ldY + j];
        a2 += xr[m + 2] * d.Y[(size_t)(m + 2) * d.ldY + j];
        a3 += xr[m + 3] * d.Y[(size_t)(m + 3) * d.ldY + j];
    }
    d.Z[(size_t)i * d.ldZ + j] = (a0 + a1) + (a2 + a3);
}

/* ---- u -> bf16 convert ---- */
__global__ __launch_bounds__(256) void ubf_kernel(const float* __restrict__ u,
                                                  unsigned short* __restrict__ ub) {
    const size_t total = (size_t)BATCH * T_LEN * NU / 4;
    for (size_t idx = (size_t)blockIdx.x * blockDim.x + threadIdx.x; idx < total;
         idx += (size_t)gridDim.x * blockDim.x) {
        float4 v = ((const float4*)u)[idx];
        unsigned short o0 = f2bf(v.x), o1 = f2bf(v.y), o2 = f2bf(v.z), o3 = f2bf(v.w);
        unsigned long long pack = (unsigned long long)o0 | ((unsigned long long)o1 << 16)
                                | ((unsigned long long)o2 << 32) | ((unsigned long long)o3 << 48);
        ((unsigned long long*)ub)[idx] = pack;
    }
}

/* ---- assemble WT[o=k*64+yi][f 0..319] bf16 ----
   f<128: D_k[yi][f] (D0 = C); f in u_j block: k>j ? P_{k-1-j}[yi][f'] : 0 */
__global__ __launch_bounds__(320) void wassm_kernel(const float* __restrict__ Dm,
                                                    const float* __restrict__ C,
                                                    const float* __restrict__ Pm,
                                                    unsigned short* __restrict__ WT) {
    int o = blockIdx.x;      // 0..255
    int f = threadIdx.x;     // 0..319
    int k = o >> 6, yi = o & 63;
    float v = 0.f;
    if (f < 128) {
        v = (k == 0) ? C[(size_t)yi * NX + f] : Dm[(size_t)(k - 1) * 64 * NX + (size_t)yi * NX + f];
    } else {
        int j = (f - 128) >> 6, e = (f - 128) & 63;
        if (k > j) v = Pm[(size_t)(k - 1 - j) * 64 * 64 + (size_t)yi * 64 + e];
    }
    WT[(size_t)o * 320 + f] = f2bf(v);
}

/* ---- K4: phase 1, R=4 blocked: z <- A4 z + G u4; 16 iters ---- */
__global__ __launch_bounds__(512, 4) void phase1_kernel(const float* __restrict__ u_,
                                                        const float* __restrict__ A4,
                                                        const float* __restrict__ G,
                                                        float* __restrict__ L) {
    int t = threadIdx.x;
    int g = t >> 4, seg = t & 15;
    int pair = blockIdx.x;
    int c = pair >> 5, b = pair & 31;
    const float* urow = u_ + ((size_t)b * T_LEN + (size_t)c * KCH) * NU;

    float4 A4r[4][2], Gr[4][4];
#pragma unroll
    for (int r = 0; r < 4; ++r) {
        const float4* ap = (const float4*)(A4 + (size_t)(g + 32 * r) * NX + seg * 8);
        A4r[r][0] = ap[0]; A4r[r][1] = ap[1];
        const float4* gp = (const float4*)(G + (size_t)(g + 32 * r) * 256 + seg * 16);
        Gr[r][0] = gp[0]; Gr[r][1] = gp[1]; Gr[r][2] = gp[2]; Gr[r][3] = gp[3];
    }

    __shared__ __align__(16) float xs[2][192];
    __shared__ __align__(16) float us[2][320];
    if (t < NX) xs[0][XP(t)] = 0.f;
    float up = (t < 256) ? urow[t] : 0.f;

    int buf = 0;
    for (int m = 0; m < 16; ++m) {
        if (t < 256) us[buf][UP16(t)] = up;
        if (t < 256 && m < 15) up = urow[(size_t)(m + 1) * 256 + t];
        __syncthreads();
        const float4* xq = (const float4*)&xs[buf][seg * 12];
        float4 xa = xq[0], xb = xq[1];
        const float4* uq = (const float4*)&us[buf][seg * 20];
        float acc0[4], acc1[4];
#pragma unroll
        for (int r = 0; r < 4; ++r) {
            acc0[r] = A4r[r][0].x * xa.x + A4r[r][0].y * xa.y
                    + A4r[r][0].z * xa.z + A4r[r][0].w * xa.w;
            acc1[r] = A4r[r][1].x * xb.x + A4r[r][1].y * xb.y
                    + A4r[r][1].z * xb.z + A4r[r][1].w * xb.w;
        }
#pragma unroll
        for (int q = 0; q < 4; ++q) {
            float4 uv = uq[q];
#pragma unroll
            for (int r = 0; r < 4; ++r) {
                float pr = Gr[r][q].x * uv.x + Gr[r][q].y * uv.y
                         + Gr[r][q].z * uv.z + Gr[r][q].w * uv.w;
                if (q & 1) acc1[r] += pr; else acc0[r] += pr;
            }
        }
        float acc[4];
#pragma unroll
        for (int r = 0; r < 4; ++r) acc[r] = acc0[r] + acc1[r];
#pragma unroll
        for (int d = 1; d <= 8; d <<= 1) {
#pragma unroll
            for (int r = 0; r < 4; ++r) acc[r] += __shfl_xor(acc[r], d);
        }
        if (seg == 0) {
            xs[buf ^ 1][XP(g)]      = acc[0];
            xs[buf ^ 1][XP(g + 32)] = acc[1];
            xs[buf ^ 1][XP(g + 64)] = acc[2];
            xs[buf ^ 1][XP(g + 96)] = acc[3];
        }
        buf ^= 1;
    }
    __syncthreads();
    if (t < NX) L[(size_t)pair * NX + t] = xs[buf][XP(t)];
}

/* ---- K5: phase 2 — chunk-level recurrence Xc[c+1] = A^64 Xc[c] + L[c] ---- */
__global__ __launch_bounds__(128) void phase2_kernel(const float* __restrict__ AK,
                                                     const float* __restrict__ L,
                                                     const float* __restrict__ x0,
                                                     float* __restrict__ Xc) {
    __shared__ float Ks[NX][NX + 1];
    __shared__ float xs[NX];
    int tid = threadIdx.x, b = blockIdx.x;
    for (int idx = tid; idx < NX * NX; idx += 128)
        Ks[idx >> 7][idx & 127] = AK[idx];
    float x = x0[tid];
    xs[tid] = x;
    Xc[(size_t)(0 * BATCH + b) * NX + tid] = x;
    __syncthreads();
    for (int c = 0; c < NC - 1; ++c) {
        float a0 = 0.f, a1 = 0.f, a2 = 0.f, a3 = 0.f;
        for (int j = 0; j < NX; j += 4) {
            a0 += Ks[tid][j]     * xs[j];
            a1 += Ks[tid][j + 1] * xs[j + 1];
            a2 += Ks[tid][j + 2] * xs[j + 2];
            a3 += Ks[tid][j + 3] * xs[j + 3];
        }
        float xn = (a0 + a1) + (a2 + a3) + L[((size_t)c * BATCH + b) * NX + tid];
        __syncthreads();
        xs[tid] = xn;
        Xc[((size_t)(c + 1) * BATCH + b) * NX + tid] = xn;
        __syncthreads();
    }
}

/* ---- K6: phase 3 chain, R=4, init from Xc; writes x_{4m} (bf16) ---- */
__global__ __launch_bounds__(512, 4) void phase3c_kernel(const float* __restrict__ u_,
                                                         const float* __restrict__ A4,
                                                         const float* __restrict__ G,
                                                         const float* __restrict__ Xc,
                                                         unsigned short* __restrict__ X4) {
    int t = threadIdx.x;
    int g = t >> 4, seg = t & 15;
    int pair = blockIdx.x;
    int c = pair >> 5, b = pair & 31;
    const float* urow = u_ + ((size_t)b * T_LEN + (size_t)c * KCH) * NU;

    float4 A4r[4][2], Gr[4][4];
#pragma unroll
    for (int r = 0; r < 4; ++r) {
        const float4* ap = (const float4*)(A4 + (size_t)(g + 32 * r) * NX + seg * 8);
        A4r[r][0] = ap[0]; A4r[r][1] = ap[1];
        const float4* gp = (const float4*)(G + (size_t)(g + 32 * r) * 256 + seg * 16);
        Gr[r][0] = gp[0]; Gr[r][1] = gp[1]; Gr[r][2] = gp[2]; Gr[r][3] = gp[3];
    }

    __shared__ __align__(16) float xs[2][192];
    __shared__ __align__(16) float us[2][320];
    if (t < NX) xs[0][XP(t)] = Xc[(size_t)pair * NX + t];
    float up = (t < 256) ? urow[t] : 0.f;

    int buf = 0;
    for (int m = 0; m < 16; ++m) {
        if (t < 256) us[buf][UP16(t)] = up;
        if (t < 256 && m < 15) up = urow[(size_t)(m + 1) * 256 + t];
        __syncthreads();
        /* emit x_{4m} (producers wrote pre-barrier) */
        if (t < NX) X4[((size_t)pair * 16 + m) * NX + t] = f2bf(xs[buf][XP(t)]);
        const float4* xq = (const float4*)&xs[buf][seg * 12];
        float4 xa = xq[0], xb = xq[1];
        const float4* uq = (const float4*)&us[buf][seg * 20];
        float acc0[4], acc1[4];
#pragma unroll
        for (int r = 0; r < 4; ++r) {
            acc0[r] = A4r[r][0].x * xa.x + A4r[r][0].y * xa.y
                    + A4r[r][0].z * xa.z + A4r[r][0].w * xa.w;
            acc1[r] = A4r[r][1].x * xb.x + A4r[r][1].y * xb.y
                    + A4r[r][1].z * xb.z + A4r[r][1].w * xb.w;
        }
#pragma unroll
        for (int q = 0; q < 4; ++q) {
            float4 uv = uq[q];
#pragma unroll
            for (int r = 0; r < 4; ++r) {
                float pr = Gr[r][q].x * uv.x + Gr[r][q].y * uv.y
                         + Gr[r][q].z * uv.z + Gr[r][q].w * uv.w;
                if (q & 1) acc1[r] += pr; else acc0[r] += pr;
            }
        }
        float acc[4];
#pragma unroll
        for (int r = 0; r < 4; ++r) acc[r] = acc0[r] + acc1[r];
#pragma unroll
        for (int d = 1; d <= 8; d <<= 1) {
#pragma unroll
            for (int r = 0; r < 4; ++r) acc[r] += __shfl_xor(acc[r], d);
        }
        if (seg == 0) {
            xs[buf ^ 1][XP(g)]      = acc[0];
            xs[buf ^ 1][XP(g + 32)] = acc[1];
            xs[buf ^ 1][XP(g + 64)] = acc[2];
            xs[buf ^ 1][XP(g + 96)] = acc[3];
        }
        buf ^= 1;
    }
}

/* ---- K7: MFMA y-emit: rows (pair,m), feats [x4(128)|u0|u1|u2(192)],
   cols o = k*64+yi; y[4m+k][yi] = feats @ WT[o][:].
   Block = 64 rows, 4 waves (wave w -> cols w*64..+63). No LDS, no barriers. */
__global__ __launch_bounds__(256) void yemit_mfma_kernel(const unsigned short* __restrict__ X4,
                                                         const unsigned short* __restrict__ ub,
                                                         const unsigned short* __restrict__ WT,
                                                         float* __restrict__ y) {
    int t = threadIdx.x;
    int w = t >> 6, l = t & 63;
    int l16 = l & 15, l4 = l >> 4;
    int blk = blockIdx.x;

    f32x4 acc[4][4];
#pragma unroll
    for (int mt = 0; mt < 4; ++mt)
#pragma unroll
        for (int nt = 0; nt < 4; ++nt) acc[mt][nt] = (f32x4){0.f, 0.f, 0.f, 0.f};

    int grow[4];
    const unsigned short* ubase[4];
#pragma unroll
    for (int mt = 0; mt < 4; ++mt) {
        grow[mt] = blk * 64 + mt * 16 + l16;
        int pair = grow[mt] >> 4, m = grow[mt] & 15;
        int b = pair & 31, cc = pair >> 5;
        ubase[mt] = ub + ((size_t)b * T_LEN + (size_t)cc * KCH + 4 * m) * NU;
    }

#pragma unroll
    for (int kt = 0; kt < 10; ++kt) {
        int feat = kt * 32 + l4 * 8;
        bf16x8 afr[4];
#pragma unroll
        for (int mt = 0; mt < 4; ++mt) {
            const unsigned short* ap;
            if (feat < 128) {
                ap = X4 + (size_t)grow[mt] * NX + feat;
            } else {
                int fu = feat - 128;
                ap = ubase[mt] + (size_t)(fu >> 6) * NU + (fu & 63);
            }
            afr[mt] = *(const bf16x8*)ap;
        }
        bf16x8 bfr[4];
#pragma unroll
        for (int nt = 0; nt < 4; ++nt) {
            int o = w * 64 + nt * 16 + l16;
            bfr[nt] = *(const bf16x8*)(WT + (size_t)o * 320 + kt * 32 + l4 * 8);
        }
#pragma unroll
        for (int mt = 0; mt < 4; ++mt)
#pragma unroll
            for (int nt = 0; nt < 4; ++nt)
                acc[mt][nt] = __builtin_amdgcn_mfma_f32_16x16x32_bf16(
                    afr[mt], bfr[nt], acc[mt][nt], 0, 0, 0);
    }

#pragma unroll
    for (int mt = 0; mt < 4; ++mt) {
#pragma unroll
        for (int nt = 0; nt < 4; ++nt) {
            int o = w * 64 + nt * 16 + l16;
            int k = o >> 6, yi = o & 63;
#pragma unroll
            for (int reg = 0; reg < 4; ++reg) {
                int r = blk * 64 + mt * 16 + l4 * 4 + reg;
                int pair = r >> 4, m = r & 15;
                int b = pair & 31, cc = pair >> 5;
                int tt = cc * KCH + 4 * m + k;
                y[((size_t)b * T_LEN + tt) * NY + yi] = acc[mt][nt][reg];
            }
        }
    }
}

/* ---- K6b (fallback): serial phase3 with inline y-emit (fp32) ---- */
__global__ __launch_bounds__(256) void phase3_fb_kernel(const float* __restrict__ u_,
                                                        const float* __restrict__ A,
                                                        const float* __restrict__ Bm,
                                                        const float* __restrict__ C,
                                                        const float* __restrict__ Xc,
                                                        float* __restrict__ y) {
    int t = threadIdx.x;
    int i = t >> 1, h = t & 1;
    int r = t >> 2, q = t & 3;
    int pair = blockIdx.x;
    int c = pair >> 5, b = pair & 31;
    const float* urow = u_ + ((size_t)b * T_LEN + (size_t)c * KCH) * NU;
    float* yrow = y + ((size_t)b * T_LEN + (size_t)c * KCH) * NY;
    float Ar[64];
    {
        const float4* Arow = (const float4*)(A + (size_t)i * NX + h * 64);
#pragma unroll
        for (int j4 = 0; j4 < 16; ++j4) {
            float4 v = Arow[j4];
            Ar[4 * j4] = v.x; Ar[4 * j4 + 1] = v.y; Ar[4 * j4 + 2] = v.z; Ar[4 * j4 + 3] = v.w;
        }
    }
    float Br[32];
    {
        const float4* Brow = (const float4*)(Bm + (size_t)i * NU + h * 32);
#pragma unroll
        for (int j4 = 0; j4 < 8; ++j4) {
            float4 v = Brow[j4];
            Br[4 * j4] = v.x; Br[4 * j4 + 1] = v.y; Br[4 * j4 + 2] = v.z; Br[4 * j4 + 3] = v.w;
        }
    }
    float Cr[32];
    {
        const float4* Crow = (const float4*)(C + (size_t)r * NX + q * 32);
#pragma unroll
        for (int j4 = 0; j4 < 8; ++j4) {
            float4 v = Crow[j4];
            Cr[4 * j4] = v.x; Cr[4 * j4 + 1] = v.y; Cr[4 * j4 + 2] = v.z; Cr[4 * j4 + 3] = v.w;
        }
    }
    __shared__ float xs[2][NX];
    __shared__ float us[2][NU];
    if (h == 0) xs[0][i] = Xc[(size_t)pair * NX + i];
    float up = (t < NU) ? urow[t] : 0.f;
    __syncthreads();
    {
        float c0 = 0.f, c1 = 0.f, c2 = 0.f, c3 = 0.f;
        const float* xp = &xs[0][q * 32];
#pragma unroll
        for (int j = 0; j < 32; j += 4) {
            c0 += Cr[j]     * xp[j];
            c1 += Cr[j + 1] * xp[j + 1];
            c2 += Cr[j + 2] * xp[j + 2];
            c3 += Cr[j + 3] * xp[j + 3];
        }
        float s = (c0 + c1) + (c2 + c3);
        s += __shfl_xor(s, 1);
        s += __shfl_xor(s, 2);
        if (q == 0) yrow[r] = s;
    }
    int buf = 0;
    for (int k = 1; k < KCH; ++k) {
        if (t < NU) us[buf][t] = up;
        if (k < KCH - 1 && t < NU) up = urow[(size_t)k * NU + t];
        __syncthreads();
        float a0 = 0.f, a1 = 0.f, a2 = 0.f, a3 = 0.f;
        const float* xp = &xs[buf][h * 64];
        const float* upp = &us[buf][h * 32];
#pragma unroll
        for (int j = 0; j < 64; j += 4) {
            a0 += Ar[j]     * xp[j];
            a1 += Ar[j + 1] * xp[j + 1];
            a2 += Ar[j + 2] * xp[j + 2];
            a3 += Ar[j + 3] * xp[j + 3];
        }
#pragma unroll
        for (int j = 0; j < 32; j += 4) {
            a0 += Br[j]     * upp[j];
            a1 += Br[j + 1] * upp[j + 1];
            a2 += Br[j + 2] * upp[j + 2];
            a3 += Br[j + 3] * upp[j + 3];
        }
        float a = (a0 + a1) + (a2 + a3);
        float s = a + __shfl_xor(a, 1);
        if (h == 0) xs[buf ^ 1][i] = s;
        __syncthreads();
        float c0 = 0.f, c1 = 0.f, c2 = 0.f, c3 = 0.f;
        const float* xcp = &xs[buf ^ 1][q * 32];
#pragma unroll
        for (int j = 0; j < 32; j += 4) {
            c0 += Cr[j]     * xcp[j];
            c1 += Cr[j + 1] * xcp[j + 1];
            c2 += Cr[j + 2] * xcp[j + 2];
            c3 += Cr[j + 3] * xcp[j + 3];
        }
        float sy = (c0 + c1) + (c2 + c3);
        sy += __shfl_xor(sy, 1);
        sy += __shfl_xor(sy, 2);
        if (q == 0) yrow[(size_t)k * NY + r] = sy;
        buf ^= 1;
    }
}

extern "C" void kernel_launch(void* const* d_in, const int* in_sizes, int n_in,
                              void* d_out, int out_size, void* d_ws, size_t ws_size,
                              hipStream_t stream) {
    const float* u_  = (const float*)d_in[0];
    const float* M   = (const float*)d_in[1];
    const float* Bm  = (const float*)d_in[2];
    const float* C   = (const float*)d_in[3];
    const float* x0  = (const float*)d_in[4];
    float* y = (float*)d_out;
    float* ws = (float*)d_ws;

    float* E   = ws + OFF_E;
    float* F   = ws + OFF_F;
    float* A   = ws + OFF_A;
    float* A2  = ws + OFF_E;   /* reuse */
    float* A4  = ws + OFF_F;   /* reuse */
    float* G   = ws + OFF_G;
    float* P0b = ws + OFF_P0;
    float* P1b = ws + OFF_P1;
    float* Dm  = ws + OFF_D;   /* D1,D2,D3 */
    float* Pm  = ws + OFF_P;   /* P0,P1,P2 */
    unsigned short* WT = (unsigned short*)(ws + OFF_WT);
    float* Xc  = ws + OFF_XC;
    float* L   = ws + OFF_L;
    unsigned short* X4 = (unsigned short*)(ws + OFF_X4);
    unsigned short* UB = (unsigned short*)(ws + OFF_UB);

    bool fast = ws_size >= (size_t)WS_NEED_FLOATS * sizeof(float);

    ef_kernel<<<dim3(128, 2), 128, 0, stream>>>(M, E, F);
    solve_kernel<<<1, 256, 0, stream>>>(E, F, A);

    /* stage 1: A2 = A*A; G[:,128:192] = A*B; G[:,192:256] = B */
    {
        MM3 mm;
        mm.d[0] = { A, A, A2,            128, NX, NX, NX,  128 };
        mm.d[1] = { A, Bm, G + 128,       64, NX, NU, 256, 128 };
        mm.d[2] = { Bm, nullptr, G + 192, 64, NU, 0, 256,  128 };
        mm_batch_kernel<<<dim3(128, 3), 128, 0, stream>>>(mm);
    }
    /* stage 2: A4 = A2*A2; G[:,0:64] = A2*(AB); G[:,64:128] = A2*B */
    {
        MM3 mm;
        mm.d[0] = { A2, A2, A4,      128, NX, NX, NX,   128 };
        mm.d[1] = { A2, G + 128, G,   64, NX, 256, 256, 128 };
        mm.d[2] = { A2, Bm, G + 64,   64, NX, NU, 256,  128 };
        mm_batch_kernel<<<dim3(128, 3), 128, 0, stream>>>(mm);
    }
    /* D1=C@A, P0=C@B */
    {
        MM3 mm;
        mm.d[0] = { C, A, Dm,        128, NX, NX, NX, 64 };
        mm.d[1] = { C, Bm, Pm,        64, NX, NU, 64, 64 };
        mm.d[2] = { nullptr, nullptr, nullptr, 0, 0, 0, 0, 0 };
        mm_batch_kernel<<<dim3(64, 3), 128, 0, stream>>>(mm);
    }
    /* D2=D1@A, P1=D1@B */
    {
        MM3 mm;
        mm.d[0] = { Dm, A, Dm + 64 * NX,  128, NX, NX, NX, 64 };
        mm.d[1] = { Dm, Bm, Pm + 64 * 64,  64, NX, NU, 64, 64 };
        mm.d[2] = { nullptr, nullptr, nullptr, 0, 0, 0, 0, 0 };
        mm_batch_kernel<<<dim3(64, 3), 128, 0, stream>>>(mm);
    }
    /* D3=D2@A, P2=D2@B */
    {
        MM3 mm;
        mm.d[0] = { Dm + 64 * NX, A, Dm + 128 * NX,   128, NX, NX, NX, 64 };
        mm.d[1] = { Dm + 64 * NX, Bm, Pm + 128 * 64,   64, NX, NU, 64, 64 };
        mm.d[2] = { nullptr, nullptr, nullptr, 0, 0, 0, 0, 0 };
        mm_batch_kernel<<<dim3(64, 3), 128, 0, stream>>>(mm);
    }
    wassm_kernel<<<256, 320, 0, stream>>>(Dm, C, Pm, WT);

    /* A64 by squaring: A8, A16, A32, A64 (ends in P1b) */
    matmul128_kernel<<<128, 128, 0, stream>>>(A4, A4, P0b);
    matmul128_kernel<<<128, 128, 0, stream>>>(P0b, P0b, P1b);
    matmul128_kernel<<<128, 128, 0, stream>>>(P1b, P1b, P0b);
    matmul128_kernel<<<128, 128, 0, stream>>>(P0b, P0b, P1b);

    phase1_kernel<<<NC * BATCH, 512, 0, stream>>>(u_, A4, G, L);
    phase2_kernel<<<BATCH, 128, 0, stream>>>(P1b, L, x0, Xc);

    if (fast) {
        ubf_kernel<<<2048, 256, 0, stream>>>(u_, UB);
        phase3c_kernel<<<NC * BATCH, 512, 0, stream>>>(u_, A4, G, Xc, X4);
        yemit_mfma_kernel<<<NC * BATCH * 16 / 64, 256, 0, stream>>>(X4, UB, WT, y);
    } else {
        phase3_fb_kernel<<<NC * BATCH, 256, 0, stream>>>(u_, A, Bm, C, Xc, y);
    }
}